// Round 11
// baseline (94.938 us; speedup 1.0000x reference)
//
#include <hip/hip_runtime.h>

// Output layout (floats): [0]=loss, [1..8388608]=quantized BCHW,
// [8388609]=perplexity, [8388610..]=encodings (N x K)
#define QUANT_OFF 1
#define PERP_OFF 8388609
#define ENC_OFF  8388610

// ws: [0,2048)    counts u32[512]
//     [2048,4096) sw2 f32[512]
//     [4096,8192) loss partials f32[1024]
//     [8192,73728)   w2 bf16[512*64]  (-2W)
//     [73728,598016) idx u32[131072]

typedef __attribute__((ext_vector_type(8))) short bf16x8;
typedef __attribute__((ext_vector_type(2))) float f32x2;
typedef __attribute__((ext_vector_type(4))) float f32x4;

__device__ __forceinline__ unsigned short f2bf(float f) {
  unsigned int u = __float_as_uint(f);
  u += 0x7fffu + ((u >> 16) & 1u);
  return (unsigned short)(u >> 16);
}

// 512 blocks x 64 thr: sw2, bf16(-2W) pack, counts zeroing
__global__ void vq_prep(const float* __restrict__ W, float* __restrict__ sw2,
                        unsigned short* __restrict__ w2,
                        unsigned int* __restrict__ counts) {
  int k = blockIdx.x;
  int d = threadIdx.x;
  float wd = W[k * 64 + d];
  w2[k * 64 + d] = f2bf(-2.0f * wd);
  float s = wd * wd;
  #pragma unroll
  for (int off = 32; off; off >>= 1) s += __shfl_down(s, off, 64);
  if (d == 0) { sw2[k] = s; counts[k] = 0u; }
}

// 512 thr = 8 waves; wave owns 32 points; block = 256 points; grid = 512.
// PHASE-SPLIT: set A (points rl) computes + streams its 16 enc rows, THEN
// set B computes while A's stores drain -> write BW overlaps compute.
__global__ __launch_bounds__(512, 4) void vq_argmin(
    const float* __restrict__ x, const unsigned short* __restrict__ w2,
    const float* __restrict__ sw2g, unsigned int* __restrict__ idx,
    unsigned int* __restrict__ counts, float* __restrict__ lpart,
    float* __restrict__ out) {
  __shared__ unsigned short wlds[512 * 72];  // 73728 B, padded rows
  __shared__ float sw2s[512];
  __shared__ unsigned int hcnt[512];
  __shared__ float lred[8];

  int tid  = threadIdx.x;
  int lane = tid & 63;
  int wv   = tid >> 6;
  int rl   = lane & 15;        // column (point-in-set) / code-row-in-tile
  int g    = lane >> 4;        // k-group (8 dims) / acc row-group
  int n0   = (blockIdx.x << 8) + (wv << 5);   // wave's first point (32/wave)
  int b    = n0 >> 12;         // 256-pt blocks never cross a batch
  int hw0  = n0 & 4095;
  const float* xb = x + b * 262144 + hw0;     // channel stride 4096

  hcnt[tid] = 0u;
  sw2s[tid] = sw2g[tid];

  // x load + bf16 convert, two point sets (rl and rl+16)
  bf16x8 xfA0, xfA1, xfB0, xfB1;
  float cnA = 0.0f, cnB = 0.0f;
  #pragma unroll
  for (int e = 0; e < 8; ++e) {
    int d0 = (g * 8 + e) * 4096, d1 = (32 + g * 8 + e) * 4096;
    float a0 = xb[d0 + rl],      a1 = xb[d1 + rl];
    float b0 = xb[d0 + 16 + rl], b1 = xb[d1 + 16 + rl];
    cnA = fmaf(a0, a0, fmaf(a1, a1, cnA));
    cnB = fmaf(b0, b0, fmaf(b1, b1, cnB));
    xfA0[e] = f2bf(a0); xfA1[e] = f2bf(a1);
    xfB0[e] = f2bf(b0); xfB1[e] = f2bf(b1);
  }
  cnA += __shfl_xor(cnA, 16); cnA += __shfl_xor(cnA, 32);
  cnB += __shfl_xor(cnB, 16); cnB += __shfl_xor(cnB, 32);

  // stage pre-packed bf16 (-2W) into padded LDS (unit = 16B = 8 bf16)
  #pragma unroll
  for (int i = 0; i < 8; ++i) {
    int u = (i << 9) + tid;          // 4096 units
    int r = u >> 3, c = u & 7;
    bf16x8 v = *(const bf16x8*)&w2[u * 8];
    *(bf16x8*)&wlds[r * 72 + c * 8] = v;
  }
  __syncthreads();

  int rowoff = rl * 72 + g * 8;
  f32x2* encw = (f32x2*)(out + ENC_OFF) + ((long long)n0 << 8);

  // ---------------- PHASE A: set A compute + its enc rows ----------------
  float bestA = __uint_as_float(0x7f7fffffu);
  #pragma unroll
  for (int t = 0; t < 32; ++t) {
    f32x4 acc = *(const f32x4*)&sw2s[t * 16 + g * 4];
    int tb = t * 1152 + rowoff;
    bf16x8 a0 = *(const bf16x8*)&wlds[tb];
    bf16x8 a1 = *(const bf16x8*)&wlds[tb + 32];
    acc = __builtin_amdgcn_mfma_f32_16x16x32_bf16(a0, xfA0, acc, 0, 0, 0);
    acc = __builtin_amdgcn_mfma_f32_16x16x32_bf16(a1, xfA1, acc, 0, 0, 0);
    #pragma unroll
    for (int j = 0; j < 4; ++j) {
      unsigned int pk = (__float_as_uint(acc[j]) & ~511u)
                        | (unsigned int)(t * 16 + g * 4 + j);
      bestA = fminf(bestA, __uint_as_float(pk));
    }
  }
  bestA = fminf(bestA, __shfl_xor(bestA, 16));
  bestA = fminf(bestA, __shfl_xor(bestA, 32));
  int biA = __float_as_uint(bestA) & 511;
  float scoreA = __uint_as_float(__float_as_uint(bestA) & ~511u);

  // stream set A's 16 one-hot rows (32KB contiguous, fire-and-forget)
  #pragma unroll 4
  for (int r = 0; r < 16; ++r) {
    int rb = __shfl(biA, r);
    f32x2* rowp = encw + (r << 8);
    #pragma unroll
    for (int q = 0; q < 4; ++q) {
      int ci = ((q << 6) + lane) << 1;
      f32x2 v;
      v.x = (rb == ci)     ? 1.0f : 0.0f;
      v.y = (rb == ci + 1) ? 1.0f : 0.0f;
      rowp[(q << 6) + lane] = v;
    }
  }

  // ---------------- PHASE B: set B computes while A's stores drain -------
  float bestB = __uint_as_float(0x7f7fffffu);
  #pragma unroll
  for (int t = 0; t < 32; ++t) {
    f32x4 acc = *(const f32x4*)&sw2s[t * 16 + g * 4];
    int tb = t * 1152 + rowoff;
    bf16x8 a0 = *(const bf16x8*)&wlds[tb];
    bf16x8 a1 = *(const bf16x8*)&wlds[tb + 32];
    acc = __builtin_amdgcn_mfma_f32_16x16x32_bf16(a0, xfB0, acc, 0, 0, 0);
    acc = __builtin_amdgcn_mfma_f32_16x16x32_bf16(a1, xfB1, acc, 0, 0, 0);
    #pragma unroll
    for (int j = 0; j < 4; ++j) {
      unsigned int pk = (__float_as_uint(acc[j]) & ~511u)
                        | (unsigned int)(t * 16 + g * 4 + j);
      bestB = fminf(bestB, __uint_as_float(pk));
    }
  }
  bestB = fminf(bestB, __shfl_xor(bestB, 16));
  bestB = fminf(bestB, __shfl_xor(bestB, 32));
  int biB = __float_as_uint(bestB) & 511;
  float scoreB = __uint_as_float(__float_as_uint(bestB) & ~511u);

  #pragma unroll 4
  for (int r = 0; r < 16; ++r) {
    int rb = __shfl(biB, r);
    f32x2* rowp = encw + ((16 + r) << 8);
    #pragma unroll
    for (int q = 0; q < 4; ++q) {
      int ci = ((q << 6) + lane) << 1;
      f32x2 v;
      v.x = (rb == ci)     ? 1.0f : 0.0f;
      v.y = (rb == ci + 1) ? 1.0f : 0.0f;
      rowp[(q << 6) + lane] = v;
    }
  }

  // ---------------- bookkeeping ----------------
  if (lane < 16) {
    idx[n0 + rl] = (unsigned int)biA;
    atomicAdd(&hcnt[biA], 1u);
  } else if (lane < 32) {
    idx[n0 + 16 + rl] = (unsigned int)biB;
    atomicAdd(&hcnt[biB], 1u);
  }

  float dl = (cnA + scoreA) + (cnB + scoreB);
  #pragma unroll
  for (int off = 1; off < 64; off <<= 1) dl += __shfl_xor(dl, off);
  if (lane == 0) lred[wv] = dl * 0.25f;

  __syncthreads();
  if (tid == 0) {
    float s = 0.0f;
    #pragma unroll
    for (int i = 0; i < 8; ++i) s += lred[i];
    lpart[blockIdx.x] = s;
  }
  unsigned int hv = hcnt[tid];
  if (hv) atomicAdd(&counts[tid], hv);
}

// Quant (contiguous 64KB/block streams) + fused finalizer (block 512).
__global__ __launch_bounds__(256) void vq_write(
    const float* __restrict__ W, const unsigned int* __restrict__ idx,
    const unsigned int* __restrict__ counts, const float* __restrict__ lpart,
    float* __restrict__ out) {
  int bid = blockIdx.x;
  int tid = threadIdx.x;
  if (bid < 512) {
    float* quant = out + QUANT_OFF;
    int e0 = bid << 14;                    // 16384 elems per block
    #pragma unroll 4
    for (int i = 0; i < 64; ++i) {
      int e = e0 + (i << 8) + tid;
      int b = e >> 18, ch = (e >> 12) & 63, hw = e & 4095;
      int n = (b << 12) | hw;
      quant[e] = W[(idx[n] << 6) | ch];
    }
  } else {
    // finalizer: 256 threads cover 512 codes / 512 loss partials
    __shared__ float red[4], red2[4];
    float pr0 = (float)counts[tid]       * (1.0f / 131072.0f);
    float pr1 = (float)counts[tid + 256] * (1.0f / 131072.0f);
    float s = pr0 * logf(pr0 + 1e-10f) + pr1 * logf(pr1 + 1e-10f);
    float l = lpart[tid] + lpart[tid + 256];
    #pragma unroll
    for (int off = 32; off; off >>= 1) {
      s += __shfl_down(s, off, 64);
      l += __shfl_down(l, off, 64);
    }
    if ((tid & 63) == 0) { red[tid >> 6] = s; red2[tid >> 6] = l; }
    __syncthreads();
    if (tid == 0) {
      float H = 0.0f, L = 0.0f;
      #pragma unroll
      for (int i = 0; i < 4; ++i) { H += red[i]; L += red2[i]; }
      out[PERP_OFF] = expf(-H);
      out[0] = 1.25f * L * (1.0f / 8388608.0f);
    }
  }
}

extern "C" void kernel_launch(void* const* d_in, const int* in_sizes, int n_in,
                              void* d_out, int out_size, void* d_ws, size_t ws_size,
                              hipStream_t stream) {
  (void)in_sizes; (void)n_in; (void)out_size; (void)ws_size;
  const float* x = (const float*)d_in[0];
  const float* W = (const float*)d_in[1];
  float* out = (float*)d_out;

  char* ws = (char*)d_ws;
  unsigned int* counts = (unsigned int*)ws;
  float* sw2           = (float*)(ws + 2048);
  float* lpart         = (float*)(ws + 4096);
  unsigned short* w2   = (unsigned short*)(ws + 8192);
  unsigned int* idx    = (unsigned int*)(ws + 73728);

  vq_prep<<<512, 64, 0, stream>>>(W, sw2, w2, counts);
  vq_argmin<<<512, 512, 0, stream>>>(x, w2, sw2, idx, counts, lpart, out);
  vq_write<<<513, 256, 0, stream>>>(W, idx, counts, lpart, out);
}